// Round 19
// baseline (908.041 us; speedup 1.0000x reference)
//
#include <hip/hip_runtime.h>
#include <hip/hip_bf16.h>

typedef __attribute__((ext_vector_type(8))) short short8;
typedef __attribute__((ext_vector_type(4))) float f32x4;

#define GLOAD_LDS16(gp, lp)                                                      \
  __builtin_amdgcn_global_load_lds(                                              \
      (const __attribute__((address_space(1))) void*)(gp),                       \
      (__attribute__((address_space(3))) void*)(lp), 16, 0, 0)

#define SBAR() asm volatile("s_barrier" ::: "memory")
#define VMC(n)                                                                   \
  do {                                                                           \
    asm volatile("s_waitcnt vmcnt(" #n ")" ::: "memory");                        \
    __builtin_amdgcn_sched_barrier(0);                                           \
  } while (0)

__device__ __forceinline__ unsigned short f2bf_rne(float f) {
  union { float f; unsigned int u; } v; v.f = f;
  unsigned int u = v.u;
  u += 0x7fffu + ((u >> 16) & 1u);
  return (unsigned short)(u >> 16);
}

__device__ __forceinline__ short8 pack8(f32x4 a, f32x4 b) {
  short8 o;
  o[0] = (short)f2bf_rne(a[0]); o[1] = (short)f2bf_rne(a[1]);
  o[2] = (short)f2bf_rne(a[2]); o[3] = (short)f2bf_rne(a[3]);
  o[4] = (short)f2bf_rne(b[0]); o[5] = (short)f2bf_rne(b[1]);
  o[6] = (short)f2bf_rne(b[2]); o[7] = (short)f2bf_rne(b[3]);
  return o;
}

// ---- fused prep: xb = bf16(x); T = mask*2*(x@A^T); Wb = bf16(W);
//      Bwb = bf16(Bw) (blocks < 64) ----
__global__ __launch_bounds__(256) void cvt_lora_kernel(
    const float* __restrict__ x,     // [16384][4096] f32
    const float* __restrict__ A,     // [32][4096]    f32
    const float* __restrict__ W,     // [4096][4096]  f32
    const float* __restrict__ Bw,    // [4096][32]    f32
    const int* __restrict__ offs,    // [4]
    unsigned short* __restrict__ xb, // [16384][4096] bf16 out
    unsigned short* __restrict__ Wb, // [4096][4096]  bf16 out
    unsigned short* __restrict__ Bwb,// [4096][32]    bf16 out
    unsigned short* __restrict__ T)  // [16384][32]   bf16 out
{
  __shared__ unsigned short xs[32 * 72];
  __shared__ unsigned short as_[32 * 72];
  const int t = threadIdx.x;
  const int m0 = blockIdx.x * 32;
  const int l = t & 63, w = t >> 6;
  const int wr = w >> 1, wc = w & 1;
  const int lr = l & 15, lk = (l >> 4) * 8;
  const int arow = t >> 3, acol = (t & 7) * 8;

  if (blockIdx.x < 64) {
    int idx = blockIdx.x * 256 + t;
    const f32x4* s4b = (const f32x4*)Bw;
    ((short8*)Bwb)[idx] = pack8(s4b[2 * idx], s4b[2 * idx + 1]);
  }

  const float* px = x + (size_t)(m0 + arow) * 4096 + acol;
  const float* pa = A + (size_t)arow * 4096 + acol;
  f32x4 vx0 = *(const f32x4*)px, vx1 = *(const f32x4*)(px + 4);
  f32x4 va0 = *(const f32x4*)pa, va1 = *(const f32x4*)(pa + 4);

  f32x4 acc = {0, 0, 0, 0};
  for (int kt = 0; kt < 64; ++kt) {
    short8 s0 = pack8(vx0, vx1);
    short8 sa = pack8(va0, va1);
    if (kt < 63) {
      px += 64; pa += 64;
      vx0 = *(const f32x4*)px; vx1 = *(const f32x4*)(px + 4);
      va0 = *(const f32x4*)pa; va1 = *(const f32x4*)(pa + 4);
    }
    *(short8*)(xb + (size_t)(m0 + arow) * 4096 + kt * 64 + acol) = s0;
    __syncthreads();
    *(short8*)&xs[arow * 72 + acol]  = s0;
    *(short8*)&as_[arow * 72 + acol] = sa;
    __syncthreads();
#pragma unroll
    for (int kk = 0; kk < 2; ++kk) {
      short8 a = *(const short8*)&xs[(wr * 16 + lr) * 72 + kk * 32 + lk];
      short8 b = *(const short8*)&as_[(wc * 16 + lr) * 72 + kk * 32 + lk];
      acc = __builtin_amdgcn_mfma_f32_16x16x32_bf16(a, b, acc, 0, 0, 0);
    }
  }
  const int rowb = (l >> 4) * 4;
#pragma unroll
  for (int j = 0; j < 4; ++j) {
    int m = m0 + wr * 16 + rowb + j;
    int bb = m >> 12, s = m & 4095;
    int kcut = offs[bb]; if (kcut > 4096) kcut = 4096;
    bool keep = s >= 4096 - kcut;
    T[(size_t)m * 32 + wc * 16 + lr] = keep ? f2bf_rne(2.0f * acc[j]) : (unsigned short)0;
  }
  const f32x4* s4 = (const f32x4*)W;
  short8* d8 = (short8*)Wb;
  const int base = blockIdx.x * 4096;
#pragma unroll
  for (int q = 0; q < 16; ++q) {
    int idx = base + q * 256 + t;
    d8[idx] = pack8(s4[2 * idx], s4[2 * idx + 1]);
  }
}

// ------------------------------------------------------------- main GEMM -----
// TRAFFIC CUT (not another schedule): A-operand DIRECT global->register.
// All 11 schedule variants (R6-R18) pinned at ~4500 cyc/K-tile because the
// LDS unit is the long pipe (reads 196KB@85B/cyc + DMA writes 128KB ~= 4400
// cyc >= measured).  Removing A from LDS halves both terms: B-only LDS =
// 2 slots x 32KB = 64 KiB, ~2600 cyc floor.
// A-frags: plain C++ loads (compiler-managed vmcnt -- no rule-18 exposure),
// naturally coalesced (16 rows x 16B, xb row-major, no swizzle needed),
// L2-resident (XCD swizzle sweeps 16 n-tiles per A-panel).  Double-buffer
// banks arE/arO (compile-time indices), loaded 2-6 phases before use.
// Manual VMC(8) at P3/P7 forces exactly the 4 newest B-halves (A-loads are
// the 8 newest, issued after the B-stages) -- B residency manual, A residency
// compiler.  B swizzle/read pattern unchanged (verified ZERO conflicts).
// WAR: B slots 2-barrier-separated (same as R13); A banks alternate tiles.
__global__ __launch_bounds__(512, 2) void gemm_kernel(
    const unsigned short* __restrict__ xb,   // [16384][4096] bf16
    const unsigned short* __restrict__ Wb,   // [4096][4096]  bf16
    const unsigned short* __restrict__ Tm,   // [16384][32]   bf16 (mask+scale)
    const unsigned short* __restrict__ Bwb,  // [4096][32]    bf16
    const float* __restrict__ bias,          // [4096]
    float* __restrict__ out)                 // [16384][4096] f32
{
  constexpr int K = 4096;
  extern __shared__ char smem[];             // 64 KiB: 2 slots x (B0 16K + B1 16K)

  const int bid = blockIdx.x;
  const int swz = (bid & 7) * 128 + (bid >> 3);
  const int m0 = (swz >> 4) * 256;
  const int n0 = (swz & 15) * 256;

  const int t = threadIdx.x;
  const int l = t & 63, w = t >> 6;
  const int wqr = w >> 2;
  const int pr = (w >> 1) & 1;
  const int pc = w & 1;
  const int lr = l & 15, hi = l >> 4;
  const int e0 = (hi ^ (lr & 7)) * 8;        // B-side zero-conflict swizzle

  // B staging (swizzled source, linear LDS dest) -- unchanged.
  const int srow = t >> 3;
  const int schunk = ((t & 7) ^ ((t >> 3) & 7)) * 8;
  const unsigned short* pB0 = Wb + (size_t)(n0 + srow) * K + schunk;
  const unsigned short* pB1 = Wb + (size_t)(n0 + 128 + srow) * K + schunk;
  unsigned short* sm = (unsigned short*)smem;
  const int ldst = t * 16;

#define STGB(PTR, SLOT, HALF, KT)                                               \
  do {                                                                          \
    const unsigned short* g_ = (PTR) + (KT) * 64;                               \
    char* d_ = smem + (SLOT) * 32768 + (HALF) * 16384 + ldst;                   \
    GLOAD_LDS16(g_, d_);                                                        \
    GLOAD_LDS16(g_ + (size_t)64 * K, d_ + 8192);                                \
  } while (0)

  // A direct: 4 row pointers (f-strided), kk via +32 elements, kt via +64/tile.
  const unsigned short* ap0 = xb + (size_t)(m0 + wqr * 128 + pr * 64 + lr) * K + hi * 8;
  const unsigned short* ap1 = ap0 + (size_t)16 * K;
  const unsigned short* ap2 = ap0 + (size_t)32 * K;
  const unsigned short* ap3 = ap0 + (size_t)48 * K;

  short8 arE[2][4], arO[2][4];   // [kk][f] register banks, even/odd tiles

#define LDA(BANK, KT)                                                           \
  do {                                                                          \
    BANK[0][0] = *(const short8*)(ap0 + (KT) * 64);                             \
    BANK[0][1] = *(const short8*)(ap1 + (KT) * 64);                             \
    BANK[0][2] = *(const short8*)(ap2 + (KT) * 64);                             \
    BANK[0][3] = *(const short8*)(ap3 + (KT) * 64);                             \
    BANK[1][0] = *(const short8*)(ap0 + (KT) * 64 + 32);                        \
    BANK[1][1] = *(const short8*)(ap1 + (KT) * 64 + 32);                        \
    BANK[1][2] = *(const short8*)(ap2 + (KT) * 64 + 32);                        \
    BANK[1][3] = *(const short8*)(ap3 + (KT) * 64 + 32);                        \
  } while (0)

  f32x4 acc[2][4][4];

  // --- LoRA prestep: register-direct (L2-resident), initializes acc ---
  {
    const unsigned short* tp = Tm + (size_t)(m0 + wqr * 128 + pr * 64 + lr) * 32 + hi * 8;
    short8 la[4];
#pragma unroll
    for (int i = 0; i < 4; ++i) la[i] = *(const short8*)(tp + i * 512);
    short8 lb[2][4];
#pragma unroll
    for (int qc = 0; qc < 2; ++qc)
#pragma unroll
      for (int j = 0; j < 4; ++j)
        lb[qc][j] = *(const short8*)(Bwb + (size_t)(n0 + qc * 128 + pc * 64 + j * 16 + lr) * 32 + hi * 8);
#pragma unroll
    for (int qc = 0; qc < 2; ++qc)
#pragma unroll
      for (int i = 0; i < 4; ++i)
#pragma unroll
        for (int j = 0; j < 4; ++j)
          acc[qc][i][j] = __builtin_amdgcn_mfma_f32_16x16x32_bf16(
              la[i], lb[qc][j], (f32x4){0.f, 0.f, 0.f, 0.f}, 0, 0, 0);
  }

  // prologue: stage s0.B0@0, s0.B1@0 (4 loads), then A(0) (8 loads, newest).
  // VMC(8) forces the B stages, leaves A(0) for the compiler's counted waits.
  STGB(pB0, 0, 0, 0);
  STGB(pB1, 0, 1, 0);
  LDA(arE, 0);
  VMC(8);
  SBAR();

  // Phase: 4 B ds_reads; issue (stage / A-loads); barrier; 16 MFMA; wait; barrier.
#define PHASE(SLOT, QC, KK, BANK, ISSUE_STMT, WAIT_STMT)                        \
  {                                                                             \
    const unsigned short* Bh = sm + (SLOT) * 16384 + (QC) * 8192;               \
    const int ek = e0 ^ ((KK) * 32);                                            \
    short8 bfr[4];                                                              \
    _Pragma("unroll")                                                           \
    for (int j_ = 0; j_ < 4; ++j_)                                              \
      bfr[j_] = *(const short8*)(Bh + (pc * 64 + j_ * 16 + lr) * 64 + ek);      \
    ISSUE_STMT;                                                                 \
    SBAR();                                                                     \
    __builtin_amdgcn_s_setprio(1);                                              \
    _Pragma("unroll")                                                           \
    for (int i_ = 0; i_ < 4; ++i_)                                              \
      _Pragma("unroll")                                                         \
      for (int j_ = 0; j_ < 4; ++j_)                                            \
        acc[QC][i_][j_] = __builtin_amdgcn_mfma_f32_16x16x32_bf16(              \
            BANK[KK][i_], bfr[j_], acc[QC][i_][j_], 0, 0, 0);                   \
    __builtin_amdgcn_s_setprio(0);                                              \
    WAIT_STMT;                                                                  \
    SBAR();                                                                     \
  }

#define NOP ((void)0)

  // Iter I: tile a=2I (slot0, arE), tile a+1 (slot1, arO).
  //  P0: stage s1.B0@a+1   P1: stage s1.B1@a+1   P2: LDA(arO, a+1)
  //  P3: VMC(8)  [queue: B(a+1)x4 oldest, A(a+1)x8 newest -> forces B only]
  //  P4: stage s0.B0@a+2   P5: stage s0.B1@a+2   P6: LDA(arE, a+2)
  //  P7: VMC(8)  [forces B(a+2); leaves A(a+2)]
  for (int I = 0; I < 31; ++I) {
    const int a = 2 * I;
    PHASE(0, 0, 0, arE, STGB(pB0, 1, 0, a + 1), NOP);
    PHASE(0, 1, 0, arE, STGB(pB1, 1, 1, a + 1), NOP);
    PHASE(0, 0, 1, arE, LDA(arO, a + 1), NOP);
    PHASE(0, 1, 1, arE, NOP, VMC(8));
    PHASE(1, 0, 0, arO, STGB(pB0, 0, 0, a + 2), NOP);
    PHASE(1, 1, 0, arO, STGB(pB1, 0, 1, a + 2), NOP);
    PHASE(1, 0, 1, arO, LDA(arE, a + 2), NOP);
    PHASE(1, 1, 1, arO, NOP, VMC(8));
  }
  // tail I=31 (tiles 62, 63): stage/load tile 63 only; then bare.
  PHASE(0, 0, 0, arE, STGB(pB0, 1, 0, 63), NOP);
  PHASE(0, 1, 0, arE, STGB(pB1, 1, 1, 63), NOP);
  PHASE(0, 0, 1, arE, LDA(arO, 63), NOP);
  PHASE(0, 1, 1, arE, NOP, VMC(8));
  PHASE(1, 0, 0, arO, NOP, NOP);
  PHASE(1, 1, 0, arO, NOP, NOP);
  PHASE(1, 0, 1, arO, NOP, NOP);
  PHASE(1, 1, 1, arO, NOP, NOP);
#undef PHASE
#undef NOP
#undef STGB
#undef LDA

  // epilogue: bias + store (C/D map: col=lr -> N, row=hi*4+e -> M)
  float bv[2][4];
#pragma unroll
  for (int qc = 0; qc < 2; ++qc)
#pragma unroll
    for (int j = 0; j < 4; ++j)
      bv[qc][j] = bias[n0 + qc * 128 + pc * 64 + j * 16 + lr];
  const int rowb = hi * 4;
#pragma unroll
  for (int qc = 0; qc < 2; ++qc)
#pragma unroll
    for (int i = 0; i < 4; ++i)
#pragma unroll
      for (int e = 0; e < 4; ++e) {
        int row = m0 + wqr * 128 + pr * 64 + i * 16 + rowb + e;
        float* orow = out + (size_t)row * 4096 + n0 + qc * 128 + pc * 64;
#pragma unroll
        for (int j = 0; j < 4; ++j) orow[j * 16 + lr] = acc[qc][i][j][e] + bv[qc][j];
      }
}

// ----------------------------------------------------------------- launch ----
extern "C" void kernel_launch(void* const* d_in, const int* in_sizes, int n_in,
                              void* d_out, int out_size, void* d_ws, size_t ws_size,
                              hipStream_t stream) {
  const float* x   = (const float*)d_in[0];
  const int* offs  = (const int*)d_in[1];
  const float* W   = (const float*)d_in[2];
  const float* b   = (const float*)d_in[3];
  const float* A   = (const float*)d_in[4];
  const float* Bw  = (const float*)d_in[5];
  float* out = (float*)d_out;

  char* ws = (char*)d_ws;
  unsigned short* xb  = (unsigned short*)ws;                 // 134,217,728 B
  unsigned short* Wb  = (unsigned short*)(ws + 134217728);   //  33,554,432 B
  unsigned short* Bwb = (unsigned short*)(ws + 167772160);   //     262,144 B
  unsigned short* T   = (unsigned short*)(ws + 168034304);   //   1,048,576 B

  hipFuncSetAttribute((const void*)gemm_kernel,
                      hipFuncAttributeMaxDynamicSharedMemorySize, 65536);

  cvt_lora_kernel<<<512, 256, 0, stream>>>(x, A, W, Bw, offs, xb, Wb, Bwb, T);
  gemm_kernel<<<1024, 512, 65536, stream>>>(xb, Wb, T, Bwb, b, out);
}

// Round 20
// 565.662 us; speedup vs baseline: 1.6053x; 1.6053x over previous
//
#include <hip/hip_runtime.h>
#include <hip/hip_bf16.h>

typedef __attribute__((ext_vector_type(8))) short short8;
typedef __attribute__((ext_vector_type(4))) float f32x4;

#define GLOAD_LDS16(gp, lp)                                                      \
  __builtin_amdgcn_global_load_lds(                                              \
      (const __attribute__((address_space(1))) void*)(gp),                       \
      (__attribute__((address_space(3))) void*)(lp), 16, 0, 0)

#define SBAR() asm volatile("s_barrier" ::: "memory")
#define VMC(n)                                                                   \
  do {                                                                           \
    asm volatile("s_waitcnt vmcnt(" #n ")" ::: "memory");                        \
    __builtin_amdgcn_sched_barrier(0);                                           \
  } while (0)

__device__ __forceinline__ unsigned short f2bf_rne(float f) {
  union { float f; unsigned int u; } v; v.f = f;
  unsigned int u = v.u;
  u += 0x7fffu + ((u >> 16) & 1u);
  return (unsigned short)(u >> 16);
}

__device__ __forceinline__ short8 pack8(f32x4 a, f32x4 b) {
  short8 o;
  o[0] = (short)f2bf_rne(a[0]); o[1] = (short)f2bf_rne(a[1]);
  o[2] = (short)f2bf_rne(a[2]); o[3] = (short)f2bf_rne(a[3]);
  o[4] = (short)f2bf_rne(b[0]); o[5] = (short)f2bf_rne(b[1]);
  o[6] = (short)f2bf_rne(b[2]); o[7] = (short)f2bf_rne(b[3]);
  return o;
}

// ---- fused prep: xb = bf16(x); T = mask*2*(x@A^T); Wb = bf16(W);
//      Bwb = bf16(Bw) (blocks < 64) ----
__global__ __launch_bounds__(256) void cvt_lora_kernel(
    const float* __restrict__ x,     // [16384][4096] f32
    const float* __restrict__ A,     // [32][4096]    f32
    const float* __restrict__ W,     // [4096][4096]  f32
    const float* __restrict__ Bw,    // [4096][32]    f32
    const int* __restrict__ offs,    // [4]
    unsigned short* __restrict__ xb, // [16384][4096] bf16 out
    unsigned short* __restrict__ Wb, // [4096][4096]  bf16 out
    unsigned short* __restrict__ Bwb,// [4096][32]    bf16 out
    unsigned short* __restrict__ T)  // [16384][32]   bf16 out
{
  __shared__ unsigned short xs[32 * 72];
  __shared__ unsigned short as_[32 * 72];
  const int t = threadIdx.x;
  const int m0 = blockIdx.x * 32;
  const int l = t & 63, w = t >> 6;
  const int wr = w >> 1, wc = w & 1;
  const int lr = l & 15, lk = (l >> 4) * 8;
  const int arow = t >> 3, acol = (t & 7) * 8;

  if (blockIdx.x < 64) {
    int idx = blockIdx.x * 256 + t;
    const f32x4* s4b = (const f32x4*)Bw;
    ((short8*)Bwb)[idx] = pack8(s4b[2 * idx], s4b[2 * idx + 1]);
  }

  const float* px = x + (size_t)(m0 + arow) * 4096 + acol;
  const float* pa = A + (size_t)arow * 4096 + acol;
  f32x4 vx0 = *(const f32x4*)px, vx1 = *(const f32x4*)(px + 4);
  f32x4 va0 = *(const f32x4*)pa, va1 = *(const f32x4*)(pa + 4);

  f32x4 acc = {0, 0, 0, 0};
  for (int kt = 0; kt < 64; ++kt) {
    short8 s0 = pack8(vx0, vx1);
    short8 sa = pack8(va0, va1);
    if (kt < 63) {                        // prefetch next iteration
      px += 64; pa += 64;
      vx0 = *(const f32x4*)px; vx1 = *(const f32x4*)(px + 4);
      va0 = *(const f32x4*)pa; va1 = *(const f32x4*)(pa + 4);
    }
    *(short8*)(xb + (size_t)(m0 + arow) * 4096 + kt * 64 + acol) = s0;
    __syncthreads();
    *(short8*)&xs[arow * 72 + acol]  = s0;
    *(short8*)&as_[arow * 72 + acol] = sa;
    __syncthreads();
#pragma unroll
    for (int kk = 0; kk < 2; ++kk) {
      short8 a = *(const short8*)&xs[(wr * 16 + lr) * 72 + kk * 32 + lk];
      short8 b = *(const short8*)&as_[(wc * 16 + lr) * 72 + kk * 32 + lk];
      acc = __builtin_amdgcn_mfma_f32_16x16x32_bf16(a, b, acc, 0, 0, 0);
    }
  }
  const int rowb = (l >> 4) * 4;
#pragma unroll
  for (int j = 0; j < 4; ++j) {
    int m = m0 + wr * 16 + rowb + j;
    int bb = m >> 12, s = m & 4095;
    int kcut = offs[bb]; if (kcut > 4096) kcut = 4096;
    bool keep = s >= 4096 - kcut;
    T[(size_t)m * 32 + wc * 16 + lr] = keep ? f2bf_rne(2.0f * acc[j]) : (unsigned short)0;
  }
  const f32x4* s4 = (const f32x4*)W;
  short8* d8 = (short8*)Wb;
  const int base = blockIdx.x * 4096;
#pragma unroll
  for (int q = 0; q < 16; ++q) {
    int idx = base + q * 256 + t;
    d8[idx] = pack8(s4[2 * idx], s4[2 * idx + 1]);
  }
}

// ------------------------------------------------------------- main GEMM -----
// BEST MEASURED (R18): 256x256, BK=64, 2 slots, 8 waves, 16x16x32 MFMA,
// quarter-wave swizzle chunk^=(row&7) -> ZERO bank conflicts, loose counted
// waits: one half staged per phase [s1.A1, s1.B0, s1.B1, s0.A0 | s0.A1,
// s0.B0, s0.B1, s1.A0]; VMC(4) at P0/P3/P4/P7 (every forced load >=3-4
// phases old, depth-4 in flight).  ~490us / 1130 TF / MfmaUtil ~53% --
// at the LDS-unit traffic floor for a both-operands-in-LDS 2562 tile
// (read volume 192KB/K-tile is minimal over all 8-wave decompositions).
__global__ __launch_bounds__(512, 2) void gemm_kernel(
    const unsigned short* __restrict__ xb,   // [16384][4096] bf16
    const unsigned short* __restrict__ Wb,   // [4096][4096]  bf16
    const unsigned short* __restrict__ Tm,   // [16384][32]   bf16 (mask+scale)
    const unsigned short* __restrict__ Bwb,  // [4096][32]    bf16
    const float* __restrict__ bias,          // [4096]
    float* __restrict__ out)                 // [16384][4096] f32
{
  constexpr int K = 4096;
  extern __shared__ char smem[];             // 128 KiB

  const int bid = blockIdx.x;
  const int swz = (bid & 7) * 128 + (bid >> 3);
  const int m0 = (swz >> 4) * 256;
  const int n0 = (swz & 15) * 256;

  const int t = threadIdx.x;
  const int l = t & 63, w = t >> 6;
  const int wqr = w >> 2;
  const int pr = (w >> 1) & 1;
  const int pc = w & 1;
  const int lr = l & 15, hi = l >> 4;
  const int e0 = (hi ^ (lr & 7)) * 8;        // verified zero-conflict swizzle

  const int srow = t >> 3;
  const int schunk = ((t & 7) ^ ((t >> 3) & 7)) * 8;
  const unsigned short* pA0 = xb + (size_t)(m0 + srow) * K + schunk;
  const unsigned short* pA1 = xb + (size_t)(m0 + 128 + srow) * K + schunk;
  const unsigned short* pB0 = Wb + (size_t)(n0 + srow) * K + schunk;
  const unsigned short* pB1 = Wb + (size_t)(n0 + 128 + srow) * K + schunk;
  unsigned short* sm = (unsigned short*)smem;
  const int ldst = t * 16;

#define STG(PTR, SLOT, ISB, HALF, KT)                                           \
  do {                                                                          \
    const unsigned short* g_ = (PTR) + (KT) * 64;                               \
    char* d_ = smem + (SLOT) * 65536 + (ISB) * 32768 + (HALF) * 16384 + ldst;   \
    GLOAD_LDS16(g_, d_);                                                        \
    GLOAD_LDS16(g_ + (size_t)64 * K, d_ + 8192);                                \
  } while (0)

  f32x4 acc[2][4][4];
  short8 afr[4];   // persists across the qc1 phase (A reuse)

  // --- LoRA prestep: register-direct (L2-resident), initializes acc ---
  {
    const unsigned short* tp = Tm + (size_t)(m0 + wqr * 128 + pr * 64 + lr) * 32 + hi * 8;
    short8 la[4];
#pragma unroll
    for (int i = 0; i < 4; ++i) la[i] = *(const short8*)(tp + i * 512);
    short8 lb[2][4];
#pragma unroll
    for (int qc = 0; qc < 2; ++qc)
#pragma unroll
      for (int j = 0; j < 4; ++j)
        lb[qc][j] = *(const short8*)(Bwb + (size_t)(n0 + qc * 128 + pc * 64 + j * 16 + lr) * 32 + hi * 8);
#pragma unroll
    for (int qc = 0; qc < 2; ++qc)
#pragma unroll
      for (int i = 0; i < 4; ++i)
#pragma unroll
        for (int j = 0; j < 4; ++j)
          acc[qc][i][j] = __builtin_amdgcn_mfma_f32_16x16x32_bf16(
              la[i], lb[qc][j], (f32x4){0.f, 0.f, 0.f, 0.f}, 0, 0, 0);
  }

  // prologue: s0 all 4 halves @0 (oldest first), s1.A0@1; VMC(4) leaves
  // {s0.B1@0, s1.A0@1} in flight, forces s0.A0/A1/B0 for P0.
  STG(pA0, 0, 0, 0, 0);
  STG(pA1, 0, 0, 1, 0);
  STG(pB0, 0, 1, 0, 0);
  STG(pB1, 0, 1, 1, 0);
  STG(pA0, 1, 0, 0, 1);
  VMC(4);
  SBAR();

#define PHASE(SLOT, QC, KK, READA, STG_STMT, WAIT_STMT)                         \
  {                                                                             \
    const unsigned short* Ah = sm + (SLOT) * 32768 + wqr * 8192;                \
    const unsigned short* Bh = sm + (SLOT) * 32768 + 16384 + (QC) * 8192;       \
    const int ek = e0 ^ ((KK) * 32);                                            \
    if (READA) {                                                                \
      _Pragma("unroll")                                                         \
      for (int i = 0; i < 4; ++i)                                               \
        afr[i] = *(const short8*)(Ah + (pr * 64 + i * 16 + lr) * 64 + ek);      \
    }                                                                           \
    short8 bfr[4];                                                              \
    _Pragma("unroll")                                                           \
    for (int j = 0; j < 4; ++j)                                                 \
      bfr[j] = *(const short8*)(Bh + (pc * 64 + j * 16 + lr) * 64 + ek);        \
    STG_STMT;                                                                   \
    SBAR();                                                                     \
    __builtin_amdgcn_s_setprio(1);                                              \
    _Pragma("unroll")                                                           \
    for (int i = 0; i < 4; ++i)                                                 \
      _Pragma("unroll")                                                         \
      for (int j = 0; j < 4; ++j)                                               \
        acc[QC][i][j] = __builtin_amdgcn_mfma_f32_16x16x32_bf16(                \
            afr[i], bfr[j], acc[QC][i][j], 0, 0, 0);                            \
    __builtin_amdgcn_s_setprio(0);                                              \
    WAIT_STMT;                                                                  \
    SBAR();                                                                     \
  }

  // steady state: I = 0..30 (tiles a=2I in slot0, a+1 in slot1)
  for (int I = 0; I < 31; ++I) {
    const int a = 2 * I;
    PHASE(0, 0, 0, 1, STG(pA1, 1, 0, 1, a + 1), VMC(4));
    PHASE(0, 1, 0, 0, STG(pB0, 1, 1, 0, a + 1), ((void)0));
    PHASE(0, 0, 1, 1, STG(pB1, 1, 1, 1, a + 1), ((void)0));
    PHASE(0, 1, 1, 0, STG(pA0, 0, 0, 0, a + 2), VMC(4));
    PHASE(1, 0, 0, 1, STG(pA1, 0, 0, 1, a + 2), VMC(4));
    PHASE(1, 1, 0, 0, STG(pB0, 0, 1, 0, a + 2), ((void)0));
    PHASE(1, 0, 1, 1, STG(pB1, 0, 1, 1, a + 2), ((void)0));
    PHASE(1, 1, 1, 0, STG(pA0, 1, 0, 0, a + 3), VMC(4));
  }
  // tail I=31 (tiles 62, 63): stage only s1 remnants @63; drain 2 -> 0.
  PHASE(0, 0, 0, 1, STG(pA1, 1, 0, 1, 63), VMC(4));
  PHASE(0, 1, 0, 0, STG(pB0, 1, 1, 0, 63), ((void)0));
  PHASE(0, 0, 1, 1, STG(pB1, 1, 1, 1, 63), ((void)0));
  PHASE(0, 1, 1, 0, ((void)0), VMC(2));
  PHASE(1, 0, 0, 1, ((void)0), VMC(0));
  PHASE(1, 1, 0, 0, ((void)0), ((void)0));
  PHASE(1, 0, 1, 1, ((void)0), ((void)0));
  PHASE(1, 1, 1, 0, ((void)0), ((void)0));
#undef PHASE
#undef STG

  // epilogue: bias + store (C/D map: col=lr -> N, row=hi*4+e -> M)
  float bv[2][4];
#pragma unroll
  for (int qc = 0; qc < 2; ++qc)
#pragma unroll
    for (int j = 0; j < 4; ++j)
      bv[qc][j] = bias[n0 + qc * 128 + pc * 64 + j * 16 + lr];
  const int rowb = hi * 4;
#pragma unroll
  for (int qc = 0; qc < 2; ++qc)
#pragma unroll
    for (int i = 0; i < 4; ++i)
#pragma unroll
      for (int e = 0; e < 4; ++e) {
        int row = m0 + wqr * 128 + pr * 64 + i * 16 + rowb + e;
        float* orow = out + (size_t)row * 4096 + n0 + qc * 128 + pc * 64;
#pragma unroll
        for (int j = 0; j < 4; ++j) orow[j * 16 + lr] = acc[qc][i][j][e] + bv[qc][j];
      }
}

// ----------------------------------------------------------------- launch ----
extern "C" void kernel_launch(void* const* d_in, const int* in_sizes, int n_in,
                              void* d_out, int out_size, void* d_ws, size_t ws_size,
                              hipStream_t stream) {
  const float* x   = (const float*)d_in[0];
  const int* offs  = (const int*)d_in[1];
  const float* W   = (const float*)d_in[2];
  const float* b   = (const float*)d_in[3];
  const float* A   = (const float*)d_in[4];
  const float* Bw  = (const float*)d_in[5];
  float* out = (float*)d_out;

  char* ws = (char*)d_ws;
  unsigned short* xb  = (unsigned short*)ws;                 // 134,217,728 B
  unsigned short* Wb  = (unsigned short*)(ws + 134217728);   //  33,554,432 B
  unsigned short* Bwb = (unsigned short*)(ws + 167772160);   //     262,144 B
  unsigned short* T   = (unsigned short*)(ws + 168034304);   //   1,048,576 B

  hipFuncSetAttribute((const void*)gemm_kernel,
                      hipFuncAttributeMaxDynamicSharedMemorySize, 131072);

  cvt_lora_kernel<<<512, 256, 0, stream>>>(x, A, W, Bw, offs, xb, Wb, Bwb, T);
  gemm_kernel<<<1024, 512, 131072, stream>>>(xb, Wb, T, Bwb, b, out);
}